// Round 6
// baseline (129375.952 us; speedup 1.0000x reference)
//
#include <hip/hip_runtime.h>
#include <hip/hip_bf16.h>
#include <stdint.h>

typedef __attribute__((ext_vector_type(8))) short bf16x8;
typedef __attribute__((ext_vector_type(4))) float floatx4;

// Problem constants
#define TT 512
#define BB 64
#define DD 1024
#define HH 1024
#define YS_ELEMS 33554432UL  // TT*BB*HH

// ws layout (bytes)
#define OFF_A     0UL           // A[n][m] col-major bf16: 4096*32768*2 = 256 MiB
#define OFF_XB    268435456UL   // x bf16 [32768][1024]; reused for rings/flags during lstm
#define OFF_WIT   335544320UL   // WiT bf16 [4096][1024]
#define OFF_WHT   343932928UL   // WhT bf16 [4096][1024]
#define OFF_HBUF  352321536UL   // h0 bf16 [64][1024]

// inside the dead-after-gemm1 xb region:
#define RING_STRIDE 65536UL     // per XCD-group: 2 slots x 16384B (8 rows x 1024 bf16)
#define FLAGS_OFF   0x80000UL   // per group: + g*4096; 32 flags x 64B stride
#define CNT_OFF     0x88000UL   // 8 ints (rendezvous counters)

__device__ __forceinline__ unsigned short f2bf(float f) {
  union { float f; unsigned u; } v; v.f = f;
  unsigned r = (v.u + 0x7fffu + ((v.u >> 16) & 1u)) >> 16;
  return (unsigned short)r;
}
__device__ __forceinline__ float bf2f(unsigned short s) {
  union { unsigned u; float f; } v; v.u = ((unsigned)s) << 16;
  return v.f;
}
__device__ __forceinline__ float sigm(float x) { return 1.0f / (1.0f + __expf(-x)); }
__device__ __forceinline__ float tanh_fast(float x) { return 1.0f - 2.0f / (1.0f + __expf(2.0f * x)); }
__device__ __forceinline__ float ap_get(uint2 p, int r) {
  unsigned u = (r < 2) ? p.x : p.y;
  return bf2f((unsigned short)(u >> ((r & 1) * 16)));
}
__device__ __forceinline__ void gload_lds16(const void* g, void* l) {
  __builtin_amdgcn_global_load_lds((const __attribute__((address_space(1))) void*)g,
                                   (__attribute__((address_space(3))) void*)l, 16, 0, 0);
}
// ---- L2-coherent (L1-bypass) ops: valid within one XCD only ----
__device__ __forceinline__ int ldg_b32_l2(const void* p) {
  int v;
  asm volatile("global_load_dword %0, %1, off sc0\n\ts_waitcnt vmcnt(0)"
               : "=v"(v) : "v"(p) : "memory");
  return v;
}
__device__ __forceinline__ bf16x8 ldg_b128_l2(const void* p) {
  bf16x8 v;
  asm volatile("global_load_dwordx4 %0, %1, off sc0" : "=v"(v) : "v"(p) : "memory");
  return v;
}
__device__ __forceinline__ void stg_b64_l2(void* p, uint2 v) {
  asm volatile("global_store_dwordx2 %0, %1, off sc0" :: "v"(p), "v"(v) : "memory");
}
__device__ __forceinline__ void stg_b32_l2(void* p, int v) {
  asm volatile("global_store_dword %0, %1, off sc0" :: "v"(p), "v"(v) : "memory");
}

// ---------------- fp32 -> bf16 convert (x and h0) ----------------
__global__ void convert_kernel(const float* __restrict__ x, const float* __restrict__ h0,
                               unsigned short* __restrict__ xb, unsigned short* __restrict__ hb0) {
  const long total4 = (33554432L + 65536L) / 4;
  long stride = (long)gridDim.x * blockDim.x;
  for (long i = (long)blockIdx.x * blockDim.x + threadIdx.x; i < total4; i += stride) {
    long base = i * 4;
    const float4* src;
    unsigned short* dst;
    if (base < 33554432L) { src = (const float4*)(x + base); dst = xb + base; }
    else { src = (const float4*)(h0 + (base - 33554432L)); dst = hb0 + (base - 33554432L); }
    float4 v = *src;
    uint2 p;
    p.x = (unsigned)f2bf(v.x) | ((unsigned)f2bf(v.y) << 16);
    p.y = (unsigned)f2bf(v.z) | ((unsigned)f2bf(v.w) << 16);
    *(uint2*)dst = p;
  }
}

// ---------------- transpose W [1024][4096] fp32 -> WT [4096][1024] bf16 ----------------
__global__ void transpose_kernel(const float* __restrict__ W, unsigned short* __restrict__ WT) {
  __shared__ float tile[32][33];
  int n0 = blockIdx.x * 32, k0 = blockIdx.y * 32;
  int tx = threadIdx.x & 31, ty = threadIdx.x >> 5;
#pragma unroll
  for (int r = 0; r < 4; r++)
    tile[ty + r * 8][tx] = W[(size_t)(k0 + ty + r * 8) * 4096 + n0 + tx];
  __syncthreads();
#pragma unroll
  for (int r = 0; r < 4; r++)
    WT[(size_t)(n0 + ty + r * 8) * 1024 + k0 + tx] = f2bf(tile[tx][ty + r * 8]);
}

// ---------------- Phase 1: A[m][n] = x@Wi + b, stored col-major A[n][m] bf16 ----------------
__global__ __launch_bounds__(256) void gemm1_kernel(const unsigned short* __restrict__ xb,
                                                    const unsigned short* __restrict__ wiT,
                                                    const float* __restrict__ bias,
                                                    unsigned short* __restrict__ Aws) {
  __shared__ unsigned short ldsA[128 * 32];
  __shared__ unsigned short ldsB[128 * 32];
  int id = blockIdx.x;
  int xcd = id & 7, seq = id >> 3;
  int n0 = (xcd * 4 + (seq & 3)) * 128;
  int m0 = (seq >> 2) * 128;
  int tid = threadIdx.x, w = tid >> 6, l = tid & 63;
  int wm = w & 1, wn = w >> 1;
  int c = l & 15, q = l >> 4;
  const floatx4 fz = {0.f, 0.f, 0.f, 0.f};
  floatx4 acc[4][4];
#pragma unroll
  for (int mi = 0; mi < 4; mi++)
#pragma unroll
    for (int ni = 0; ni < 4; ni++) acc[mi][ni] = fz;

  const char* gA = (const char*)xb + (size_t)(m0 + w * 32 + (l >> 2)) * 2048 + (l & 3) * 16;
  const char* gB = (const char*)wiT + (size_t)(n0 + w * 32 + (l >> 2)) * 2048 + (l & 3) * 16;
  char* lA = (char*)ldsA + (w * 32) * 64;
  char* lB = (char*)ldsB + (w * 32) * 64;

  for (int kt = 0; kt < 32; kt++) {
    gload_lds16(gA, lA);
    gload_lds16(gA + 16 * 2048, lA + 16 * 64);
    gload_lds16(gB, lB);
    gload_lds16(gB + 16 * 2048, lB + 16 * 64);
    gA += 64; gB += 64;
    __syncthreads();
    bf16x8 a[4], b[4];
#pragma unroll
    for (int mi = 0; mi < 4; mi++)
      a[mi] = *(const bf16x8*)((const char*)ldsA + (wm * 64 + mi * 16 + c) * 64 + q * 16);
#pragma unroll
    for (int ni = 0; ni < 4; ni++)
      b[ni] = *(const bf16x8*)((const char*)ldsB + (wn * 64 + ni * 16 + c) * 64 + q * 16);
#pragma unroll
    for (int mi = 0; mi < 4; mi++)
#pragma unroll
      for (int ni = 0; ni < 4; ni++)
        acc[mi][ni] = __builtin_amdgcn_mfma_f32_16x16x32_bf16(a[mi], b[ni], acc[mi][ni], 0, 0, 0);
    __syncthreads();
  }
#pragma unroll
  for (int mi = 0; mi < 4; mi++) {
#pragma unroll
    for (int ni = 0; ni < 4; ni++) {
      int n_g = n0 + wn * 64 + ni * 16 + c;
      float bn = bias[n_g];
      size_t mbase = (size_t)m0 + wm * 64 + mi * 16 + q * 4;
      floatx4 v = acc[mi][ni];
      uint2 p;
      p.x = (unsigned)f2bf(v.x + bn) | ((unsigned)f2bf(v.y + bn) << 16);
      p.y = (unsigned)f2bf(v.z + bn) | ((unsigned)f2bf(v.w + bn) << 16);
      *(uint2*)((char*)Aws + (((size_t)n_g << 15) + mbase) * 2) = p;
    }
  }
}

// ---------------- Phase 2: XCD-local persistent recurrence ----------------
// 256 blocks x 512 threads (8 waves), 1 block/CU (VGPR-forced: 128 live Wh regs).
// Rendezvous: block reads its XCD via HW_REG_XCC_ID, takes role = atomicAdd rank.
// Group g (one XCD) owns batch rows 8g..8g+7; block role r owns h-cols 32r..32r+32.
// Wave (kh, ng): k-half kh (512 K each), 2 MFMA n-tiles (ng*8..+8 cols x 4 gates),
// Wh fragments resident in 128 VGPRs. Per step: poll group flags (sc0, L2) ->
// stage 16KB h tile L2->LDS -> 32 MFMA/wave -> 2-way k-reduce (LDS) -> gates ->
// h store (write-through to L2) -> vmcnt ack -> flag. Zero cross-XCD traffic.
__global__ __launch_bounds__(512, 2) void lstm_kernel(const unsigned short* __restrict__ Aws,
                                                      const unsigned short* __restrict__ whT,
                                                      const float* __restrict__ c0,
                                                      const unsigned short* __restrict__ h0b,
                                                      char* __restrict__ xbase,
                                                      float* __restrict__ out) {
  __shared__ char smem_h[8 * 2064];      // h tile: 8 rows, pitch 2064 (bank spread)
  __shared__ float ldsR[8 * 64 * 4];     // k-reduce: [(ng*2+tile)][lane][4]
  __shared__ int srank;

  int tid = threadIdx.x, wid = tid >> 6, l = tid & 63;
  int c = l & 15, q = l >> 4;
  int kh = wid >> 2, ng = wid & 3;

  if (tid == 0) {
    int xcc;
    asm volatile("s_getreg_b32 %0, hwreg(HW_REG_XCC_ID)" : "=s"(xcc));
    xcc &= 7;
    int* cnt = (int*)(xbase + CNT_OFF);
    int r = atomicAdd(&cnt[xcc], 1) & 31;
    srank = (xcc << 8) | r;
  }
  __syncthreads();
  int xcc = srank >> 8, role = srank & 255;

  char* ring  = xbase + (size_t)xcc * RING_STRIDE;
  int*  flags = (int*)(xbase + FLAGS_OFF + (size_t)xcc * 4096);

  // ---- Wh -> registers: 2 n-tiles x 16 k-steps (this wave's k-half) ----
  bf16x8 b0r[16], b1r[16];
  {
    int cc = c & 3, gate = c >> 2;
    size_t n0 = (size_t)gate * 1024 + role * 32 + ng * 8 + cc;
    const char* w0 = (const char*)whT + n0 * 2048 + (size_t)(kh * 16) * 64 + q * 16;
    const char* w1 = w0 + 4 * 2048;
#pragma unroll
    for (int kt = 0; kt < 16; kt++) {
      b0r[kt] = *(const bf16x8*)(w0 + kt * 64);
      b1r[kt] = *(const bf16x8*)(w1 + kt * 64);
    }
  }

  // ---- c-state (meaningful on kh0 waves, lanes c<4 & q<2) ----
  float cst0[4], cst1[4];
  {
    int cc = c & 3, qq = q & 1;
    int col0 = role * 32 + ng * 8 + cc;
#pragma unroll
    for (int r = 0; r < 4; r++) {
      cst0[r] = c0[(size_t)(xcc * 8 + qq * 4 + r) * 1024 + col0];
      cst1[r] = c0[(size_t)(xcc * 8 + qq * 4 + r) * 1024 + col0 + 4];
    }
  }

  float hreg0[4], hreg1[4];

#pragma unroll 1
  for (int t = 0; t < 512; t++) {
    // 1) poll group flags (wave 0; sc0 = this XCD's L2)
    if (wid == 0 && t > 0) {
      const char* fp_ = (const char*)(flags + (l & 31) * 16);
      int probes = 0;
      for (;;) {
        int v = ldg_b32_l2(fp_);
        if (__all(v >= t)) break;
        if (((++probes) & 2047) == 0) {
          int v2 = __hip_atomic_load((const int*)fp_, __ATOMIC_ACQUIRE, __HIP_MEMORY_SCOPE_AGENT);
          if (__all(v2 >= t)) break;  // placement-anomaly valve: fail loud, not hang
        }
      }
    }
    __syncthreads();

    // 2) stage h tile (8 rows x 1024 bf16 = 16 KB) into LDS
    {
      int row = tid >> 6;
      int ch  = (tid & 63) * 32;
      char* dst = smem_h + row * 2064 + ch;
      if (t == 0) {
        const char* src = (const char*)h0b + (size_t)(xcc * 8 + row) * 2048 + ch;
        *(uint4*)dst = *(const uint4*)src;
        *(uint4*)(dst + 16) = *(const uint4*)(src + 16);
      } else {
        const char* src = ring + (size_t)(t & 1) * 16384 + (size_t)row * 2048 + ch;
        bf16x8 v0 = ldg_b128_l2(src);
        bf16x8 v1 = ldg_b128_l2(src + 16);
        asm volatile("s_waitcnt vmcnt(0)" ::: "memory");
        __builtin_amdgcn_sched_barrier(0);
        *(bf16x8*)dst = v0;
        *(bf16x8*)(dst + 16) = v1;
      }
    }

    // 3) A prefetch (kh0 waves; consumed in epilogue, hidden under K-loop)
    uint2 ap0[4], ap1[4];
    if (kh == 0) {
      int cc = c & 3, qq = q & 1;
      size_t m = (size_t)t * 64 + xcc * 8 + qq * 4;
#pragma unroll
      for (int gate = 0; gate < 4; gate++) {
        size_t n0 = (size_t)gate * 1024 + role * 32 + ng * 8 + cc;
        ap0[gate] = *(const uint2*)((const char*)Aws + ((n0 << 15) + m) * 2);
        ap1[gate] = *(const uint2*)((const char*)Aws + (((n0 + 4) << 15) + m) * 2);
      }
    }
    __syncthreads();  // h tile ready

    // 4) K-loop: 16 steps over this wave's k-half; A broadcast via (c&7)
    floatx4 acc0 = {0.f, 0.f, 0.f, 0.f}, acc1 = {0.f, 0.f, 0.f, 0.f};
    const char* ha = smem_h + (c & 7) * 2064 + (size_t)(kh * 16) * 64 + q * 16;
#pragma unroll
    for (int kt = 0; kt < 16; kt++) {
      bf16x8 a = *(const bf16x8*)(ha + kt * 64);
      acc0 = __builtin_amdgcn_mfma_f32_16x16x32_bf16(a, b0r[kt], acc0, 0, 0, 0);
      acc1 = __builtin_amdgcn_mfma_f32_16x16x32_bf16(a, b1r[kt], acc1, 0, 0, 0);
    }

    // 5) cross-k reduce: kh1 dumps partials, kh0 adds
    if (kh == 1) {
      *(floatx4*)(&ldsR[((ng * 2 + 0) * 64 + l) * 4]) = acc0;
      *(floatx4*)(&ldsR[((ng * 2 + 1) * 64 + l) * 4]) = acc1;
    }
    __syncthreads();

    if (kh == 0) {
      floatx4 r0 = *(const floatx4*)(&ldsR[((ng * 2 + 0) * 64 + l) * 4]);
      floatx4 r1 = *(const floatx4*)(&ldsR[((ng * 2 + 1) * 64 + l) * 4]);
      floatx4 z0, z1;
#pragma unroll
      for (int r = 0; r < 4; r++) { z0[r] = acc0[r] + r0[r]; z1[r] = acc1[r] + r1[r]; }

      // gather gates: g0 lanes get zi=z, zf=sx4, zg=sx8, zo=sx12
      floatx4 a40, a80, a120, a41, a81, a121;
#pragma unroll
      for (int r = 0; r < 4; r++) {
        a40[r]  = __shfl_xor(z0[r], 4);
        a80[r]  = __shfl_xor(z0[r], 8);
        a120[r] = __shfl_xor(z0[r], 12);
        a41[r]  = __shfl_xor(z1[r], 4);
        a81[r]  = __shfl_xor(z1[r], 8);
        a121[r] = __shfl_xor(z1[r], 12);
      }
#pragma unroll
      for (int r = 0; r < 4; r++) {
        float zi = z0[r]    + ap_get(ap0[0], r);
        float zf = a40[r]   + ap_get(ap0[1], r);
        float zg = a80[r]   + ap_get(ap0[2], r);
        float zo = a120[r]  + ap_get(ap0[3], r);
        float ig = sigm(zi), fg = sigm(zf), tg = tanh_fast(zg), og = sigm(zo);
        float cn = fg * cst0[r] + ig * tg;
        cst0[r] = cn; hreg0[r] = og * tanh_fast(cn);
        zi = z1[r]   + ap_get(ap1[0], r);
        zf = a41[r]  + ap_get(ap1[1], r);
        zg = a81[r]  + ap_get(ap1[2], r);
        zo = a121[r] + ap_get(ap1[3], r);
        ig = sigm(zi); fg = sigm(zf); tg = tanh_fast(zg); og = sigm(zo);
        cn = fg * cst1[r] + ig * tg;
        cst1[r] = cn; hreg1[r] = og * tanh_fast(cn);
      }

      // publish h_{t+1}: pack 4 cols via shfl, store (write-through L2), ack
      if (t < 511) {
        char* hn = ring + (size_t)((t + 1) & 1) * 16384;
#pragma unroll
        for (int r = 0; r < 4; r++) {
          unsigned u0 = f2bf(hreg0[r]);
          unsigned p1 = (unsigned)__shfl_xor((int)u0, 1);
          unsigned lo = (u0 & 0xffffu) | (p1 << 16);
          unsigned lo2 = (unsigned)__shfl_xor((int)lo, 2);
          unsigned u1 = f2bf(hreg1[r]);
          unsigned p1b = (unsigned)__shfl_xor((int)u1, 1);
          unsigned lob = (u1 & 0xffffu) | (p1b << 16);
          unsigned lo2b = (unsigned)__shfl_xor((int)lob, 2);
          if (c == 0 && q < 2) {
            int row = q * 4 + r;
            uint2 pk; pk.x = lo; pk.y = lo2;
            stg_b64_l2(hn + (size_t)row * 2048 + (role * 32 + ng * 8) * 2, pk);
            uint2 pkb; pkb.x = lob; pkb.y = lo2b;
            stg_b64_l2(hn + (size_t)row * 2048 + (role * 32 + ng * 8 + 4) * 2, pkb);
          }
        }
        asm volatile("s_waitcnt vmcnt(0)" ::: "memory");  // h committed at L2
      }
    }
    __syncthreads();  // all kh0 stores acked before flag; also ldsR WAR
    if (t < 511 && tid == 0)
      stg_b32_l2((char*)(flags + role * 16), t + 1);

    // deferred ys / final-state stores (off the intra-group critical path)
    if (kh == 0) {
#pragma unroll
      for (int r = 0; r < 4; r++) {
        float f0 = hreg0[r];
        float f1 = __shfl_xor(f0, 1);
        float f2 = __shfl_xor(f0, 2);
        float f3 = __shfl_xor(f1, 2);
        float g0 = hreg1[r];
        float g1 = __shfl_xor(g0, 1);
        float g2 = __shfl_xor(g0, 2);
        float g3 = __shfl_xor(g1, 2);
        if (c == 0 && q < 2) {
          int row = xcc * 8 + q * 4 + r;
          float4 v; v.x = f0; v.y = f1; v.z = f2; v.w = f3;
          *(float4*)(out + (size_t)t * 65536 + (size_t)row * 1024 + role * 32 + ng * 8) = v;
          float4 w; w.x = g0; w.y = g1; w.z = g2; w.w = g3;
          *(float4*)(out + (size_t)t * 65536 + (size_t)row * 1024 + role * 32 + ng * 8 + 4) = w;
        }
      }
      if (t == 511) {
#pragma unroll
        for (int r = 0; r < 4; r++) {
          float c0v = cst0[r], c1v = __shfl_xor(c0v, 1), c2v = __shfl_xor(c0v, 2);
          float c3v = __shfl_xor(c1v, 2);
          float d0 = cst1[r], d1 = __shfl_xor(d0, 1), d2 = __shfl_xor(d0, 2);
          float d3 = __shfl_xor(d1, 2);
          float h0v = hreg0[r], h1v = __shfl_xor(h0v, 1), h2v = __shfl_xor(h0v, 2);
          float h3v = __shfl_xor(h1v, 2);
          float e0 = hreg1[r], e1 = __shfl_xor(e0, 1), e2 = __shfl_xor(e0, 2);
          float e3 = __shfl_xor(e1, 2);
          if (c == 0 && q < 2) {
            int row = xcc * 8 + q * 4 + r;
            size_t bc = YS_ELEMS + (size_t)row * 1024 + role * 32 + ng * 8;
            float4 v; v.x = c0v; v.y = c1v; v.z = c2v; v.w = c3v;
            *(float4*)(out + bc) = v;
            float4 vb; vb.x = d0; vb.y = d1; vb.z = d2; vb.w = d3;
            *(float4*)(out + bc + 4) = vb;
            size_t bh = YS_ELEMS + 65536 + (size_t)row * 1024 + role * 32 + ng * 8;
            float4 w; w.x = h0v; w.y = h1v; w.z = h2v; w.w = h3v;
            *(float4*)(out + bh) = w;
            float4 wb; wb.x = e0; wb.y = e1; wb.z = e2; wb.w = e3;
            *(float4*)(out + bh + 4) = wb;
          }
        }
      }
    }
  }
}

extern "C" void kernel_launch(void* const* d_in, const int* in_sizes, int n_in,
                              void* d_out, int out_size, void* d_ws, size_t ws_size,
                              hipStream_t stream) {
  (void)in_sizes; (void)n_in; (void)out_size; (void)ws_size;
  const float* x  = (const float*)d_in[0];
  const float* c0 = (const float*)d_in[1];
  const float* h0 = (const float*)d_in[2];
  const float* Wi = (const float*)d_in[3];
  const float* Wh = (const float*)d_in[4];
  const float* b  = (const float*)d_in[5];
  float* out = (float*)d_out;
  char* ws = (char*)d_ws;
  unsigned short* Aws   = (unsigned short*)(ws + OFF_A);
  unsigned short* xb    = (unsigned short*)(ws + OFF_XB);
  unsigned short* wiT   = (unsigned short*)(ws + OFF_WIT);
  unsigned short* whT   = (unsigned short*)(ws + OFF_WHT);
  unsigned short* h0b   = (unsigned short*)(ws + OFF_HBUF);
  char* xbase = ws + OFF_XB;

  convert_kernel<<<4096, 256, 0, stream>>>(x, h0, xb, h0b);
  transpose_kernel<<<dim3(128, 32), 256, 0, stream>>>(Wi, wiT);
  transpose_kernel<<<dim3(128, 32), 256, 0, stream>>>(Wh, whT);
  gemm1_kernel<<<8192, 256, 0, stream>>>(xb, wiT, b, Aws);
  // zero flags + rendezvous counters (inside xb region -> must follow gemm1)
  hipMemsetAsync(xbase + FLAGS_OFF, 0, 0x8040, stream);
  lstm_kernel<<<256, 512, 0, stream>>>(Aws, whT, c0, h0b, xbase, out);
}